// Round 5
// baseline (810.541 us; speedup 1.0000x reference)
//
#include <hip/hip_runtime.h>

#define T_LEN 512
#define B_SZ  256
#define N_ST  128

#if defined(__has_builtin)
# if __has_builtin(__builtin_amdgcn_fdot2_f32_bf16)
#  define HAVE_DOT2 1
# endif
#endif
#ifndef HAVE_DOT2
# define HAVE_DOT2 0
#endif

typedef unsigned int uint32;
typedef __bf16 bf16x2 __attribute__((ext_vector_type(2)));

__device__ __forceinline__ uint32 bf16rn(float f) {   // RNE bf16 (no NaNs here)
    uint32 u = __builtin_bit_cast(uint32, f);
    u += 0x7fffu + ((u >> 16) & 1u);
    return u >> 16;
}
__device__ __forceinline__ uint32 pack2(float lo, float hi) {
    return bf16rn(lo) | (bf16rn(hi) << 16);
}
__device__ __forceinline__ float dot2b(uint32 a, uint32 b, float c) {
#if HAVE_DOT2
    return __builtin_amdgcn_fdot2_f32_bf16(__builtin_bit_cast(bf16x2, a),
                                           __builtin_bit_cast(bf16x2, b), c, false);
#else
    float alo = __builtin_bit_cast(float, a << 16);
    float ahi = __builtin_bit_cast(float, a & 0xffff0000u);
    float blo = __builtin_bit_cast(float, b << 16);
    float bhi = __builtin_bit_cast(float, b & 0xffff0000u);
    return fmaf(ahi, bhi, fmaf(alo, blo, c));
#endif
}

// ws layout (floats): [0..255] logZ_b ; [256..511] score_b ; [512..767] lens (int)

__global__ __launch_bounds__(64) void lengths_kernel(const unsigned char* __restrict__ mask_raw,
                                                     int* __restrict__ lens) {
    int b = blockIdx.x;   // 256 blocks
    int l = threadIdx.x;  // 64 threads
    // Detect mask encoding (mask[0][*] always true since lengths >= T/2):
    // u8: byte[1]=1 ; i32: bytes1,2=0 ; f32: 1.0f -> byte[2]=0x80
    unsigned char b1 = mask_raw[1], b2 = mask_raw[2];
    int mode = (b1 != 0) ? 0 : ((b2 != 0) ? 2 : 1);
    int cnt = 0;
    if (mode == 0) {
        #pragma unroll
        for (int k = 0; k < 8; ++k) cnt += (mask_raw[(l * 8 + k) * B_SZ + b] != 0);
    } else if (mode == 1) {
        const int* m = (const int*)mask_raw;
        #pragma unroll
        for (int k = 0; k < 8; ++k) cnt += (m[(l * 8 + k) * B_SZ + b] != 0);
    } else {
        const float* m = (const float*)mask_raw;
        #pragma unroll
        for (int k = 0; k < 8; ++k) cnt += (m[(l * 8 + k) * B_SZ + b] != 0.0f);
    }
    #pragma unroll
    for (int off = 1; off < 64; off <<= 1) cnt += __shfl_xor(cnt, off);
    if (l == 0) lens[b] = cnt;
}

// One wave per block, TWO batches per wave (independent recurrences fill each
// other's LDS-turnaround/latency stalls). Lane l owns columns 2l, 2l+1.
// E (=exp(trans), bf16-pair packed) is SHARED by both batches: 128 VGPRs.
// Delayed normalizer: scale at step t uses r0 from step t-1 (exact via Macc).
__global__ __launch_bounds__(64, 1) void forward_kernel(
        const float* __restrict__ emit,
        const float* __restrict__ trans,
        const float* __restrict__ strans,
        const float* __restrict__ etrans,
        const int* __restrict__ lens,
        float* __restrict__ logZ_out) {
    const int q  = blockIdx.x;            // 0..127 -> batches 2q, 2q+1
    const int bA = 2 * q, bB = 2 * q + 1;
    const int l  = threadIdx.x;           // 0..63
    const int c0 = 2 * l, c1 = 2 * l + 1;

    __shared__ alignas(16) uint32 aA32[64];   // bf16x2 packed a-vector, batch A
    __shared__ alignas(16) uint32 aB32[64];   // batch B

    // E0[p] = (E[2p][c0], E[2p+1][c0]) ; E1[p] = same for c1 ; p = 0..63
    uint32 E0[64], E1[64];
    #pragma unroll
    for (int p = 0; p < 64; ++p) {
        float f00 = __expf(trans[(2 * p)     * N_ST + c0]);
        float f01 = __expf(trans[(2 * p + 1) * N_ST + c0]);
        float f10 = __expf(trans[(2 * p)     * N_ST + c1]);
        float f11 = __expf(trans[(2 * p + 1) * N_ST + c1]);
        E0[p] = pack2(f00, f01);
        E1[p] = pack2(f10, f11);
    }

    const int lenA = lens[bA], lenB = lens[bB];
    const int lenmin = (lenA < lenB) ? lenA : lenB;
    const float* ebA = emit + (size_t)bA * N_ST;
    const float* ebB = emit + (size_t)bB * N_ST;
    const size_t TS = (size_t)B_SZ * N_ST;

    float aA0 = __expf(strans[c0] + ebA[c0]);
    float aA1 = __expf(strans[c1] + ebA[c1]);
    float aB0 = __expf(strans[c0] + ebB[c0]);
    float aB1 = __expf(strans[c1] + ebB[c1]);
    aA32[l] = pack2(aA0, aA1);
    aB32[l] = pack2(aB0, aB1);
    float MaccA = 0.f, MaccB = 0.f;
    float invA = 1.0f, invB = 1.0f;       // delayed normalizer (prev-step 1/r0)
    float eA0 = ebA[TS + c0], eA1 = ebA[TS + c1];   // emit[1] prefetch
    float eB0 = ebB[TS + c0], eB1 = ebB[TS + c1];

    // ---- fused main loop: both batches, ONE branch-free basic block ----
    for (int t = 1; t < lenmin; ++t) {
        const size_t tnA = (size_t)((t + 1 < lenA) ? t + 1 : lenA - 1) * TS;
        const size_t tnB = (size_t)((t + 1 < lenB) ? t + 1 : lenB - 1) * TS;
        const float enA0 = ebA[tnA + c0], enA1 = ebA[tnA + c1];
        const float enB0 = ebB[tnB + c0], enB1 = ebB[tnB + c1];
        const float eeA0 = __expf(eA0), eeA1 = __expf(eA1);
        const float eeB0 = __expf(eB0), eeB1 = __expf(eB1);

        float A00 = 0, A01 = 0, A02 = 0, A03 = 0, A10 = 0, A11 = 0, A12 = 0, A13 = 0;
        float B00 = 0, B01 = 0, B02 = 0, B03 = 0, B10 = 0, B11 = 0, B12 = 0, B13 = 0;
        #pragma unroll
        for (int p = 0; p < 16; ++p) {
            uint4 wA, wB;  // alias-safe broadcast LDS reads
            __builtin_memcpy(&wA, (const char*)aA32 + 16 * p, 16);
            __builtin_memcpy(&wB, (const char*)aB32 + 16 * p, 16);
            A00 = dot2b(wA.x, E0[4 * p + 0], A00);  A10 = dot2b(wA.x, E1[4 * p + 0], A10);
            B00 = dot2b(wB.x, E0[4 * p + 0], B00);  B10 = dot2b(wB.x, E1[4 * p + 0], B10);
            A01 = dot2b(wA.y, E0[4 * p + 1], A01);  A11 = dot2b(wA.y, E1[4 * p + 1], A11);
            B01 = dot2b(wB.y, E0[4 * p + 1], B01);  B11 = dot2b(wB.y, E1[4 * p + 1], B11);
            A02 = dot2b(wA.z, E0[4 * p + 2], A02);  A12 = dot2b(wA.z, E1[4 * p + 2], A12);
            B02 = dot2b(wB.z, E0[4 * p + 2], B02);  B12 = dot2b(wB.z, E1[4 * p + 2], B12);
            A03 = dot2b(wA.w, E0[4 * p + 3], A03);  A13 = dot2b(wA.w, E1[4 * p + 3], A13);
            B03 = dot2b(wB.w, E0[4 * p + 3], B03);  B13 = dot2b(wB.w, E1[4 * p + 3], B13);
        }
        const float rA0 = (A00 + A01) + (A02 + A03);
        const float rA1 = (A10 + A11) + (A12 + A13);
        const float rB0 = (B00 + B01) + (B02 + B03);
        const float rB1 = (B10 + B11) + (B12 + B13);
        MaccA -= __logf(invA);             // off-path bookkeeping
        MaccB -= __logf(invB);
        aA0 = eeA0 * rA0 * invA;  aA1 = eeA1 * rA1 * invA;
        aB0 = eeB0 * rB0 * invB;  aB1 = eeB1 * rB1 * invB;
        aA32[l] = pack2(aA0, aA1);         // wave-internal DS order: no barrier
        aB32[l] = pack2(aB0, aB1);
        invA = __builtin_amdgcn_rcpf(__shfl(rA0, 0));   // for NEXT step (off-path)
        invB = __builtin_amdgcn_rcpf(__shfl(rB0, 0));
        eA0 = enA0; eA1 = enA1; eB0 = enB0; eB1 = enB1;
    }

    // ---- tails: at most one of these runs ----
    for (int t = lenmin; t < lenA; ++t) {
        const size_t tn = (size_t)((t + 1 < lenA) ? t + 1 : lenA - 1) * TS;
        const float en0 = ebA[tn + c0], en1 = ebA[tn + c1];
        const float ee0 = __expf(eA0), ee1 = __expf(eA1);
        float A00 = 0, A01 = 0, A02 = 0, A03 = 0, A10 = 0, A11 = 0, A12 = 0, A13 = 0;
        #pragma unroll
        for (int p = 0; p < 16; ++p) {
            uint4 w;
            __builtin_memcpy(&w, (const char*)aA32 + 16 * p, 16);
            A00 = dot2b(w.x, E0[4 * p + 0], A00);  A10 = dot2b(w.x, E1[4 * p + 0], A10);
            A01 = dot2b(w.y, E0[4 * p + 1], A01);  A11 = dot2b(w.y, E1[4 * p + 1], A11);
            A02 = dot2b(w.z, E0[4 * p + 2], A02);  A12 = dot2b(w.z, E1[4 * p + 2], A12);
            A03 = dot2b(w.w, E0[4 * p + 3], A03);  A13 = dot2b(w.w, E1[4 * p + 3], A13);
        }
        const float r0 = (A00 + A01) + (A02 + A03);
        const float r1 = (A10 + A11) + (A12 + A13);
        MaccA -= __logf(invA);
        aA0 = ee0 * r0 * invA;  aA1 = ee1 * r1 * invA;
        aA32[l] = pack2(aA0, aA1);
        invA = __builtin_amdgcn_rcpf(__shfl(r0, 0));
        eA0 = en0; eA1 = en1;
    }
    for (int t = lenmin; t < lenB; ++t) {
        const size_t tn = (size_t)((t + 1 < lenB) ? t + 1 : lenB - 1) * TS;
        const float en0 = ebB[tn + c0], en1 = ebB[tn + c1];
        const float ee0 = __expf(eB0), ee1 = __expf(eB1);
        float B00 = 0, B01 = 0, B02 = 0, B03 = 0, B10 = 0, B11 = 0, B12 = 0, B13 = 0;
        #pragma unroll
        for (int p = 0; p < 16; ++p) {
            uint4 w;
            __builtin_memcpy(&w, (const char*)aB32 + 16 * p, 16);
            B00 = dot2b(w.x, E0[4 * p + 0], B00);  B10 = dot2b(w.x, E1[4 * p + 0], B10);
            B01 = dot2b(w.y, E0[4 * p + 1], B01);  B11 = dot2b(w.y, E1[4 * p + 1], B11);
            B02 = dot2b(w.z, E0[4 * p + 2], B02);  B12 = dot2b(w.z, E1[4 * p + 2], B12);
            B03 = dot2b(w.w, E0[4 * p + 3], B03);  B13 = dot2b(w.w, E1[4 * p + 3], B13);
        }
        const float r0 = (B00 + B01) + (B02 + B03);
        const float r1 = (B10 + B11) + (B12 + B13);
        MaccB -= __logf(invB);
        aB0 = ee0 * r0 * invB;  aB1 = ee1 * r1 * invB;
        aB32[l] = pack2(aB0, aB1);
        invB = __builtin_amdgcn_rcpf(__shfl(r0, 0));
        eB0 = en0; eB1 = en1;
    }

    // logZ per batch = Macc + log( sum_j a_j * exp(etrans_j) )
    const float x0 = __expf(etrans[c0]), x1 = __expf(etrans[c1]);
    float vA = aA0 * x0 + aA1 * x1;
    float vB = aB0 * x0 + aB1 * x1;
    #pragma unroll
    for (int off = 1; off < 64; off <<= 1) {
        vA += __shfl_xor(vA, off);
        vB += __shfl_xor(vB, off);
    }
    if (l == 0) {
        logZ_out[bA] = MaccA + __logf(vA);
        logZ_out[bB] = MaccB + __logf(vB);
    }
}

__global__ __launch_bounds__(128) void score_kernel(
        const float* __restrict__ emit,
        const int* __restrict__ target,
        const float* __restrict__ trans,
        const float* __restrict__ strans,
        const float* __restrict__ etrans,
        const int* __restrict__ lens,
        float* __restrict__ score_out) {
    const int b   = blockIdx.x;
    const int tid = threadIdx.x;  // 128
    const int len = lens[b];
    float local = 0.f;
    for (int t = tid; t < len; t += 128) {
        int tgt = target[t * B_SZ + b];
        float v = emit[(size_t)t * (B_SZ * N_ST) + b * N_ST + tgt];
        if (t > 0) v += trans[target[(t - 1) * B_SZ + b] * N_ST + tgt];
        local += v;
    }
    if (tid == 0) {
        local += strans[target[b]];
        local += etrans[target[(len - 1) * B_SZ + b]];
    }
    #pragma unroll
    for (int off = 1; off < 64; off <<= 1) local += __shfl_xor(local, off);
    __shared__ float partial[2];
    if ((tid & 63) == 0) partial[tid >> 6] = local;
    __syncthreads();
    if (tid == 0) score_out[b] = partial[0] + partial[1];
}

__global__ __launch_bounds__(256) void finalize_kernel(
        const float* __restrict__ logZ,
        const float* __restrict__ score,
        float* __restrict__ out) {
    int tid = threadIdx.x;  // 256
    float v = logZ[tid] - score[tid];
    #pragma unroll
    for (int off = 1; off < 64; off <<= 1) v += __shfl_xor(v, off);
    __shared__ float p[4];
    if ((tid & 63) == 0) p[tid >> 6] = v;
    __syncthreads();
    if (tid == 0) out[0] = (p[0] + p[1] + p[2] + p[3]) / 256.0f;
}

extern "C" void kernel_launch(void* const* d_in, const int* in_sizes, int n_in,
                              void* d_out, int out_size, void* d_ws, size_t ws_size,
                              hipStream_t stream) {
    const float*         emit   = (const float*)d_in[0];
    const int*           target = (const int*)d_in[1];
    const unsigned char* mask   = (const unsigned char*)d_in[2];
    const float*         trans  = (const float*)d_in[3];
    const float*         strans = (const float*)d_in[4];
    const float*         etrans = (const float*)d_in[5];

    float* ws     = (float*)d_ws;
    float* logZb  = ws;            // 256
    float* scoreb = ws + 256;      // 256
    int*   lens   = (int*)(ws + 512);

    lengths_kernel<<<B_SZ, 64, 0, stream>>>(mask, lens);
    forward_kernel<<<B_SZ / 2, 64, 0, stream>>>(emit, trans, strans, etrans, lens, logZb);
    score_kernel<<<B_SZ, 128, 0, stream>>>(emit, target, trans, strans, etrans, lens, scoreb);
    finalize_kernel<<<1, 256, 0, stream>>>(logZb, scoreb, (float*)d_out);
}

// Round 6
// 462.480 us; speedup vs baseline: 1.7526x; 1.7526x over previous
//
#include <hip/hip_runtime.h>

#define T_LEN 512
#define B_SZ  256
#define N_ST  128

#if defined(__has_builtin)
# if __has_builtin(__builtin_amdgcn_fdot2_f32_bf16)
#  define HAVE_DOT2 1
# endif
#endif
#ifndef HAVE_DOT2
# define HAVE_DOT2 0
#endif

typedef unsigned int u32;
typedef short s8v __attribute__((ext_vector_type(8)));   // 8 bf16 = 4 VGPR (MFMA A/B frag)
typedef float f4v __attribute__((ext_vector_type(4)));   // MFMA C/D frag
typedef __bf16 bf16x2 __attribute__((ext_vector_type(2)));

__device__ __forceinline__ u32 cvtpk(float lo, float hi) {   // (lo,hi) -> packed bf16x2, RNE
    u32 r;
    asm("v_cvt_pk_bf16_f32 %0, %1, %2" : "=v"(r) : "v"(lo), "v"(hi));
    return r;
}

__device__ __forceinline__ float dot2b(u32 a, u32 b, float c) {
#if HAVE_DOT2
    return __builtin_amdgcn_fdot2_f32_bf16(__builtin_bit_cast(bf16x2, a),
                                           __builtin_bit_cast(bf16x2, b), c, false);
#else
    float alo = __builtin_bit_cast(float, a << 16);
    float ahi = __builtin_bit_cast(float, a & 0xffff0000u);
    float blo = __builtin_bit_cast(float, b << 16);
    float bhi = __builtin_bit_cast(float, b & 0xffff0000u);
    return fmaf(ahi, bhi, fmaf(alo, blo, c));
#endif
}

// ws layout (floats): [0..255] logZ_b ; [256..511] score_b ; [512..767] lens (int)

__global__ __launch_bounds__(64) void lengths_kernel(const unsigned char* __restrict__ mask_raw,
                                                     int* __restrict__ lens) {
    int b = blockIdx.x;   // 256 blocks
    int l = threadIdx.x;  // 64 threads
    // Detect mask encoding (mask[0][*] always true since lengths >= T/2):
    // u8: byte[1]=1 ; i32: bytes1,2=0 ; f32: 1.0f -> byte[2]=0x80
    unsigned char b1 = mask_raw[1], b2 = mask_raw[2];
    int mode = (b1 != 0) ? 0 : ((b2 != 0) ? 2 : 1);
    int cnt = 0;
    if (mode == 0) {
        #pragma unroll
        for (int k = 0; k < 8; ++k) cnt += (mask_raw[(l * 8 + k) * B_SZ + b] != 0);
    } else if (mode == 1) {
        const int* m = (const int*)mask_raw;
        #pragma unroll
        for (int k = 0; k < 8; ++k) cnt += (m[(l * 8 + k) * B_SZ + b] != 0);
    } else {
        const float* m = (const float*)mask_raw;
        #pragma unroll
        for (int k = 0; k < 8; ++k) cnt += (m[(l * 8 + k) * B_SZ + b] != 0.0f);
    }
    #pragma unroll
    for (int off = 1; off < 64; off <<= 1) cnt += __shfl_xor(cnt, off);
    if (l == 0) lens[b] = cnt;
}

// Permutation of the K axis: k = 32*ks + 8*g + e  ->  state m = 16*(2*ks + e/4) + 4*g + (e&3).
// With this choice, D-frag (m89-verified: col=lane&15, row=(lane>>4)*4+reg) for m-tile
// mt=2*ks+(e>>2) delivers exactly the lane-local elements the next step's B-frag needs:
// B[ks] dwords = [pk(D_{2ks}.xy), pk(D_{2ks}.zw), pk(D_{2ks+1}.xy), pk(D_{2ks+1}.zw)].

// A[m][k] = E'[k][m] = exp(trans[pi(k)][m])  (static, 32 named frags = 128 VGPR)
__device__ __forceinline__ s8v loadA(const float* __restrict__ trans, int mt, int ks, int n, int g) {
    u32 d0, d1, d2, d3;
    const int m = 16 * mt + n;
    #define LA1(I, DST) { \
        const int e0 = 2 * (I), e1 = 2 * (I) + 1; \
        const int k0 = 16 * (2 * ks + (e0 >> 2)) + 4 * g + (e0 & 3); \
        const int k1 = 16 * (2 * ks + (e1 >> 2)) + 4 * g + (e1 & 3); \
        DST = cvtpk(__expf(trans[k0 * N_ST + m]), __expf(trans[k1 * N_ST + m])); }
    LA1(0, d0) LA1(1, d1) LA1(2, d2) LA1(3, d3)
    #undef LA1
    uint4 q; q.x = d0; q.y = d1; q.z = d2; q.w = d3;
    return __builtin_bit_cast(s8v, q);
}

// Initial B frag: a0[pi(k)] = exp(strans + emit[0]) at state m(pi(k))
__device__ __forceinline__ s8v initB(const float* __restrict__ emit0,
                                     const float* __restrict__ strans, int g, int ks) {
    u32 d0, d1, d2, d3;
    #define IB1(I, DST) { \
        const int e0 = 2 * (I), e1 = 2 * (I) + 1; \
        const int m0 = 16 * (2 * ks + (e0 >> 2)) + 4 * g + (e0 & 3); \
        const int m1 = 16 * (2 * ks + (e1 >> 2)) + 4 * g + (e1 & 3); \
        DST = cvtpk(__expf(strans[m0] + emit0[m0]), __expf(strans[m1] + emit0[m1])); }
    IB1(0, d0) IB1(1, d1) IB1(2, d2) IB1(3, d3)
    #undef IB1
    uint4 q; q.x = d0; q.y = d1; q.z = d2; q.w = d3;
    return __builtin_bit_cast(s8v, q);
}

__device__ __forceinline__ u32 xpack(const float* __restrict__ etrans, int g, int ks, int i) {
    const int e0 = 2 * i, e1 = 2 * i + 1;
    const int m0 = 16 * (2 * ks + (e0 >> 2)) + 4 * g + (e0 & 3);
    const int m1 = 16 * (2 * ks + (e1 >> 2)) + 4 * g + (e1 & 3);
    return cvtpk(__expf(etrans[m0]), __expf(etrans[m1]));
}

#define FOR_MT(X) X(0) X(1) X(2) X(3) X(4) X(5) X(6) X(7)

// One wave handles 16 batches. States: M axis natural, K axis pi-permuted.
// Per step: 32 MFMA + scale/pack/freeze. No LDS, no barriers, no cross-lane moves
// in the steady state (the pi trick makes D-layout == next B-layout per lane).
__global__ __launch_bounds__(64, 1) void forward_kernel(
        const float* __restrict__ emit,
        const float* __restrict__ trans,
        const float* __restrict__ strans,
        const float* __restrict__ etrans,
        const int* __restrict__ lens,
        float* __restrict__ logZ_out) {
    const int tile = blockIdx.x;       // 16 tiles of 16 batches
    const int l = threadIdx.x;
    const int n = l & 15;              // batch-in-tile / MFMA col
    const int g = l >> 4;              // lane group
    const int bn = tile * 16 + n;      // global batch

    const size_t TS = (size_t)B_SZ * N_ST;
    const float* ep = emit + (size_t)bn * N_ST + 4 * g;   // per-lane gather base

    // ---- static E fragments (named: force register residency) ----
    #define DECL_A(MT) s8v A##MT##_0 = loadA(trans, MT, 0, n, g); \
                       s8v A##MT##_1 = loadA(trans, MT, 1, n, g); \
                       s8v A##MT##_2 = loadA(trans, MT, 2, n, g); \
                       s8v A##MT##_3 = loadA(trans, MT, 3, n, g);
    FOR_MT(DECL_A)
    #undef DECL_A

    // ---- initial a (t=0) as B fragments ----
    s8v B0 = initB(emit + (size_t)bn * N_ST, strans, g, 0);
    s8v B1 = initB(emit + (size_t)bn * N_ST, strans, g, 1);
    s8v B2 = initB(emit + (size_t)bn * N_ST, strans, g, 2);
    s8v B3 = initB(emit + (size_t)bn * N_ST, strans, g, 3);

    // ---- lengths ----
    const int len_n = lens[bn];
    int tmax = len_n;
    #pragma unroll
    for (int off = 1; off < 16; off <<= 1) tmax = max(tmax, __shfl_xor(tmax, off));

    // ---- emit pipeline (2 deep) + EE = exp(emit[t]) * inv_applied ----
    #define DECL_P(MT) f4v LB##MT, LC##MT, EE##MT;
    FOR_MT(DECL_P)
    #undef DECL_P

    #define GATH(V, TIDX) { const float* p_ = ep + (size_t)(TIDX) * TS; \
        V##0 = *(const f4v*)(p_);       V##1 = *(const f4v*)(p_ + 16); \
        V##2 = *(const f4v*)(p_ + 32);  V##3 = *(const f4v*)(p_ + 48); \
        V##4 = *(const f4v*)(p_ + 64);  V##5 = *(const f4v*)(p_ + 80); \
        V##6 = *(const f4v*)(p_ + 96);  V##7 = *(const f4v*)(p_ + 112); }

    GATH(LB, 1)
    #define EEINIT(MT) EE##MT = f4v{__expf(LB##MT.x), __expf(LB##MT.y), __expf(LB##MT.z), __expf(LB##MT.w)};
    FOR_MT(EEINIT)
    #undef EEINIT
    GATH(LB, (tmax > 2 ? 2 : tmax - 1))

    float Macc = 0.0f;
    float sclog = 0.0f;               // -log(inv folded into current EE)

    for (int t = 1; t < tmax; ++t) {
        // prefetch emit[t+2] (used 2 iterations later at EE update)
        const int tpre = (t + 2 < tmax) ? t + 2 : tmax - 1;
        GATH(LC, tpre)

        // ---- D = E' x a : 8 independent chains of 4 chained MFMAs ----
        #define DECL_D(MT) f4v D##MT;
        FOR_MT(DECL_D)
        #undef DECL_D
        const f4v Z = {0.f, 0.f, 0.f, 0.f};
        #define MF0(MT) D##MT = __builtin_amdgcn_mfma_f32_16x16x32_bf16(A##MT##_0, B0, Z,     0, 0, 0);
        FOR_MT(MF0)
        #undef MF0
        #define MF1(MT) D##MT = __builtin_amdgcn_mfma_f32_16x16x32_bf16(A##MT##_1, B1, D##MT, 0, 0, 0);
        FOR_MT(MF1)
        #undef MF1
        #define MF2(MT) D##MT = __builtin_amdgcn_mfma_f32_16x16x32_bf16(A##MT##_2, B2, D##MT, 0, 0, 0);
        FOR_MT(MF2)
        #undef MF2
        #define MF3(MT) D##MT = __builtin_amdgcn_mfma_f32_16x16x32_bf16(A##MT##_3, B3, D##MT, 0, 0, 0);
        FOR_MT(MF3)
        #undef MF3

        const bool cond = (t < len_n);       // per-batch freeze (uniform per lane)
        Macc += cond ? sclog : 0.0f;

        // ---- scale by EE (= exp(emit[t]) * inv_prev), pack, freeze-select ----
        #define PACKKS(KS, MTa, MTb, BV) { \
            f4v sa = D##MTa * EE##MTa; \
            f4v sb = D##MTb * EE##MTb; \
            u32 w0 = cvtpk(sa.x, sa.y), w1 = cvtpk(sa.z, sa.w); \
            u32 w2 = cvtpk(sb.x, sb.y), w3 = cvtpk(sb.z, sb.w); \
            uint4 old_ = __builtin_bit_cast(uint4, BV); \
            uint4 nw_; \
            nw_.x = cond ? w0 : old_.x;  nw_.y = cond ? w1 : old_.y; \
            nw_.z = cond ? w2 : old_.z;  nw_.w = cond ? w3 : old_.w; \
            BV = __builtin_bit_cast(s8v, nw_); }
        PACKKS(0, 0, 1, B0)
        PACKKS(1, 2, 3, B1)
        PACKKS(2, 4, 5, B2)
        PACKKS(3, 6, 7, B3)
        #undef PACKKS

        // ---- delayed normalizer for next step: inv = 1 / D[state 0][batch n] ----
        const float d00 = __shfl(D0.x, n);            // D[m=0][n] lives in lanes g=0
        const float inv_c = __builtin_amdgcn_rcpf(d00);
        sclog = -__logf(inv_c);
        // EE_next = exp(emit[t+1]) * inv_c ; shift pipeline LB <- LC
        #define EEUPD(MT) EE##MT = f4v{__expf(LB##MT.x) * inv_c, __expf(LB##MT.y) * inv_c, \
                                       __expf(LB##MT.z) * inv_c, __expf(LB##MT.w) * inv_c}; \
                          LB##MT = LC##MT;
        FOR_MT(EEUPD)
        #undef EEUPD
    }

    // ---- logZ_n = Macc_n + log( sum_k a[k] * exp(etrans[pi(k)]) ) ----
    float v = 0.0f;
    #define FDOT(KS) { uint4 bw = __builtin_bit_cast(uint4, B##KS); \
        v = dot2b(bw.x, xpack(etrans, g, KS, 0), v); \
        v = dot2b(bw.y, xpack(etrans, g, KS, 1), v); \
        v = dot2b(bw.z, xpack(etrans, g, KS, 2), v); \
        v = dot2b(bw.w, xpack(etrans, g, KS, 3), v); }
    FDOT(0) FDOT(1) FDOT(2) FDOT(3)
    #undef FDOT
    v += __shfl_xor(v, 16);
    v += __shfl_xor(v, 32);
    if (l < 16) logZ_out[bn] = Macc + __logf(v);
    #undef GATH
}

__global__ __launch_bounds__(128) void score_kernel(
        const float* __restrict__ emit,
        const int* __restrict__ target,
        const float* __restrict__ trans,
        const float* __restrict__ strans,
        const float* __restrict__ etrans,
        const int* __restrict__ lens,
        float* __restrict__ score_out) {
    const int b   = blockIdx.x;
    const int tid = threadIdx.x;  // 128
    const int len = lens[b];
    float local = 0.f;
    for (int t = tid; t < len; t += 128) {
        int tgt = target[t * B_SZ + b];
        float v = emit[(size_t)t * (B_SZ * N_ST) + b * N_ST + tgt];
        if (t > 0) v += trans[target[(t - 1) * B_SZ + b] * N_ST + tgt];
        local += v;
    }
    if (tid == 0) {
        local += strans[target[b]];
        local += etrans[target[(len - 1) * B_SZ + b]];
    }
    #pragma unroll
    for (int off = 1; off < 64; off <<= 1) local += __shfl_xor(local, off);
    __shared__ float partial[2];
    if ((tid & 63) == 0) partial[tid >> 6] = local;
    __syncthreads();
    if (tid == 0) score_out[b] = partial[0] + partial[1];
}

__global__ __launch_bounds__(256) void finalize_kernel(
        const float* __restrict__ logZ,
        const float* __restrict__ score,
        float* __restrict__ out) {
    int tid = threadIdx.x;  // 256
    float v = logZ[tid] - score[tid];
    #pragma unroll
    for (int off = 1; off < 64; off <<= 1) v += __shfl_xor(v, off);
    __shared__ float p[4];
    if ((tid & 63) == 0) p[tid >> 6] = v;
    __syncthreads();
    if (tid == 0) out[0] = (p[0] + p[1] + p[2] + p[3]) / 256.0f;
}

extern "C" void kernel_launch(void* const* d_in, const int* in_sizes, int n_in,
                              void* d_out, int out_size, void* d_ws, size_t ws_size,
                              hipStream_t stream) {
    const float*         emit   = (const float*)d_in[0];
    const int*           target = (const int*)d_in[1];
    const unsigned char* mask   = (const unsigned char*)d_in[2];
    const float*         trans  = (const float*)d_in[3];
    const float*         strans = (const float*)d_in[4];
    const float*         etrans = (const float*)d_in[5];

    float* ws     = (float*)d_ws;
    float* logZb  = ws;            // 256
    float* scoreb = ws + 256;      // 256
    int*   lens   = (int*)(ws + 512);

    lengths_kernel<<<B_SZ, 64, 0, stream>>>(mask, lens);
    forward_kernel<<<B_SZ / 16, 64, 0, stream>>>(emit, trans, strans, etrans, lens, logZb);
    score_kernel<<<B_SZ, 128, 0, stream>>>(emit, target, trans, strans, etrans, lens, scoreb);
    finalize_kernel<<<1, 256, 0, stream>>>(logZb, scoreb, (float*)d_out);
}

// Round 7
// 452.391 us; speedup vs baseline: 1.7917x; 1.0223x over previous
//
#include <hip/hip_runtime.h>

#define T_LEN 512
#define B_SZ  256
#define N_ST  128

#if defined(__has_builtin)
# if __has_builtin(__builtin_amdgcn_fdot2_f32_bf16)
#  define HAVE_DOT2 1
# endif
#endif
#ifndef HAVE_DOT2
# define HAVE_DOT2 0
#endif

typedef unsigned int u32;
typedef short s8v __attribute__((ext_vector_type(8)));   // 8 bf16 = 4 VGPR (MFMA A/B frag)
typedef float f4v __attribute__((ext_vector_type(4)));   // MFMA C/D frag
typedef __bf16 bf16x2 __attribute__((ext_vector_type(2)));

__device__ __forceinline__ u32 cvtpk(float lo, float hi) {   // (lo,hi) -> packed bf16x2, RNE
    u32 r;
    asm("v_cvt_pk_bf16_f32 %0, %1, %2" : "=v"(r) : "v"(lo), "v"(hi));
    return r;
}

__device__ __forceinline__ float dot2b(u32 a, u32 b, float c) {
#if HAVE_DOT2
    return __builtin_amdgcn_fdot2_f32_bf16(__builtin_bit_cast(bf16x2, a),
                                           __builtin_bit_cast(bf16x2, b), c, false);
#else
    float alo = __builtin_bit_cast(float, a << 16);
    float ahi = __builtin_bit_cast(float, a & 0xffff0000u);
    float blo = __builtin_bit_cast(float, b << 16);
    float bhi = __builtin_bit_cast(float, b & 0xffff0000u);
    return fmaf(ahi, bhi, fmaf(alo, blo, c));
#endif
}

// ws layout (floats): [0..255] logZ_b ; [256..511] score_b ; [512..767] lens (int)

__global__ __launch_bounds__(64) void lengths_kernel(const unsigned char* __restrict__ mask_raw,
                                                     int* __restrict__ lens) {
    int b = blockIdx.x;   // 256 blocks
    int l = threadIdx.x;  // 64 threads
    // Detect mask encoding (mask[0][*] always true since lengths >= T/2):
    // u8: byte[1]=1 ; i32: bytes1,2=0 ; f32: 1.0f -> byte[2]=0x80
    unsigned char b1 = mask_raw[1], b2 = mask_raw[2];
    int mode = (b1 != 0) ? 0 : ((b2 != 0) ? 2 : 1);
    int cnt = 0;
    if (mode == 0) {
        #pragma unroll
        for (int k = 0; k < 8; ++k) cnt += (mask_raw[(l * 8 + k) * B_SZ + b] != 0);
    } else if (mode == 1) {
        const int* m = (const int*)mask_raw;
        #pragma unroll
        for (int k = 0; k < 8; ++k) cnt += (m[(l * 8 + k) * B_SZ + b] != 0);
    } else {
        const float* m = (const float*)mask_raw;
        #pragma unroll
        for (int k = 0; k < 8; ++k) cnt += (m[(l * 8 + k) * B_SZ + b] != 0.0f);
    }
    #pragma unroll
    for (int off = 1; off < 64; off <<= 1) cnt += __shfl_xor(cnt, off);
    if (l == 0) lens[b] = cnt;
}

// Permutation of the K axis: k = 32*ks + 8*g + e  ->  state m = 16*(2*ks + e/4) + 4*g + (e&3).
// With this choice, D-frag (m89-verified: col=lane&15, row=(lane>>4)*4+reg) for m-tile
// mt=2*ks+(e>>2) delivers exactly the lane-local elements the next step's B-frag needs:
// B[ks] dwords = [pk(D_{2ks}.xy), pk(D_{2ks}.zw), pk(D_{2ks+1}.xy), pk(D_{2ks+1}.zw)].

// A[m][k] = E'[k][m] = exp(trans[pi(k)][m])  (static, 32 named frags = 128 VGPR)
__device__ __forceinline__ s8v loadA(const float* __restrict__ trans, int mt, int ks, int n, int g) {
    u32 d0, d1, d2, d3;
    const int m = 16 * mt + n;
    #define LA1(I, DST) { \
        const int e0 = 2 * (I), e1 = 2 * (I) + 1; \
        const int k0 = 16 * (2 * ks + (e0 >> 2)) + 4 * g + (e0 & 3); \
        const int k1 = 16 * (2 * ks + (e1 >> 2)) + 4 * g + (e1 & 3); \
        DST = cvtpk(__expf(trans[k0 * N_ST + m]), __expf(trans[k1 * N_ST + m])); }
    LA1(0, d0) LA1(1, d1) LA1(2, d2) LA1(3, d3)
    #undef LA1
    uint4 q; q.x = d0; q.y = d1; q.z = d2; q.w = d3;
    return __builtin_bit_cast(s8v, q);
}

// Initial B frag: a0[pi(k)] = exp(strans + emit[0]) at state m(pi(k))
__device__ __forceinline__ s8v initB(const float* __restrict__ emit0,
                                     const float* __restrict__ strans, int g, int ks) {
    u32 d0, d1, d2, d3;
    #define IB1(I, DST) { \
        const int e0 = 2 * (I), e1 = 2 * (I) + 1; \
        const int m0 = 16 * (2 * ks + (e0 >> 2)) + 4 * g + (e0 & 3); \
        const int m1 = 16 * (2 * ks + (e1 >> 2)) + 4 * g + (e1 & 3); \
        DST = cvtpk(__expf(strans[m0] + emit0[m0]), __expf(strans[m1] + emit0[m1])); }
    IB1(0, d0) IB1(1, d1) IB1(2, d2) IB1(3, d3)
    #undef IB1
    uint4 q; q.x = d0; q.y = d1; q.z = d2; q.w = d3;
    return __builtin_bit_cast(s8v, q);
}

__device__ __forceinline__ u32 xpack(const float* __restrict__ etrans, int g, int ks, int i) {
    const int e0 = 2 * i, e1 = 2 * i + 1;
    const int m0 = 16 * (2 * ks + (e0 >> 2)) + 4 * g + (e0 & 3);
    const int m1 = 16 * (2 * ks + (e1 >> 2)) + 4 * g + (e1 & 3);
    return cvtpk(__expf(etrans[m0]), __expf(etrans[m1]));
}

#define FOR_MT(X) X(0) X(1) X(2) X(3) X(4) X(5) X(6) X(7)

// One wave handles 16 batches. States: M axis natural, K axis pi-permuted.
// Per step: 32 MFMA + scale/pack/freeze. No LDS, no barriers, no cross-lane moves
// in the steady state (the pi trick makes D-layout == next B-layout per lane).
// amdgpu_waves_per_eu(1,1): force the register allocator to the full 512-VGPR
// budget (launch_bounds min-waves alone let it target high occupancy and SPILL
// the ~290-reg working set -> R6's VGPR=144 + scratch thrash).
__global__ void __attribute__((amdgpu_flat_work_group_size(64, 64), amdgpu_waves_per_eu(1, 1)))
forward_kernel(
        const float* __restrict__ emit,
        const float* __restrict__ trans,
        const float* __restrict__ strans,
        const float* __restrict__ etrans,
        const int* __restrict__ lens,
        float* __restrict__ logZ_out) {
    const int tile = blockIdx.x;       // 16 tiles of 16 batches
    const int l = threadIdx.x;
    const int n = l & 15;              // batch-in-tile / MFMA col
    const int g = l >> 4;              // lane group
    const int bn = tile * 16 + n;      // global batch

    const size_t TS = (size_t)B_SZ * N_ST;
    const float* ep = emit + (size_t)bn * N_ST + 4 * g;   // per-lane gather base

    // ---- static E fragments (named: force register residency) ----
    #define DECL_A(MT) s8v A##MT##_0 = loadA(trans, MT, 0, n, g); \
                       s8v A##MT##_1 = loadA(trans, MT, 1, n, g); \
                       s8v A##MT##_2 = loadA(trans, MT, 2, n, g); \
                       s8v A##MT##_3 = loadA(trans, MT, 3, n, g);
    FOR_MT(DECL_A)
    #undef DECL_A

    // ---- initial a (t=0) as B fragments ----
    s8v B0 = initB(emit + (size_t)bn * N_ST, strans, g, 0);
    s8v B1 = initB(emit + (size_t)bn * N_ST, strans, g, 1);
    s8v B2 = initB(emit + (size_t)bn * N_ST, strans, g, 2);
    s8v B3 = initB(emit + (size_t)bn * N_ST, strans, g, 3);

    // ---- lengths ----
    const int len_n = lens[bn];
    int tmax = len_n;
    #pragma unroll
    for (int off = 1; off < 16; off <<= 1) tmax = max(tmax, __shfl_xor(tmax, off));

    // ---- emit pipeline (2 deep) + EE = exp(emit[t]) * inv_applied ----
    #define DECL_P(MT) f4v LB##MT, LC##MT, EE##MT;
    FOR_MT(DECL_P)
    #undef DECL_P

    #define GATH(V, TIDX) { const float* p_ = ep + (size_t)(TIDX) * TS; \
        V##0 = *(const f4v*)(p_);       V##1 = *(const f4v*)(p_ + 16); \
        V##2 = *(const f4v*)(p_ + 32);  V##3 = *(const f4v*)(p_ + 48); \
        V##4 = *(const f4v*)(p_ + 64);  V##5 = *(const f4v*)(p_ + 80); \
        V##6 = *(const f4v*)(p_ + 96);  V##7 = *(const f4v*)(p_ + 112); }

    GATH(LB, 1)
    #define EEINIT(MT) EE##MT = f4v{__expf(LB##MT.x), __expf(LB##MT.y), __expf(LB##MT.z), __expf(LB##MT.w)};
    FOR_MT(EEINIT)
    #undef EEINIT
    GATH(LB, (tmax > 2 ? 2 : tmax - 1))

    float Macc = 0.0f;
    float sclog = 0.0f;               // -log(inv folded into current EE)

    for (int t = 1; t < tmax; ++t) {
        // prefetch emit[t+2] (used 2 iterations later at EE update)
        const int tpre = (t + 2 < tmax) ? t + 2 : tmax - 1;
        GATH(LC, tpre)

        // ---- D = E' x a : 8 independent chains of 4 chained MFMAs ----
        #define DECL_D(MT) f4v D##MT;
        FOR_MT(DECL_D)
        #undef DECL_D
        const f4v Z = {0.f, 0.f, 0.f, 0.f};
        #define MF0(MT) D##MT = __builtin_amdgcn_mfma_f32_16x16x32_bf16(A##MT##_0, B0, Z,     0, 0, 0);
        FOR_MT(MF0)
        #undef MF0
        #define MF1(MT) D##MT = __builtin_amdgcn_mfma_f32_16x16x32_bf16(A##MT##_1, B1, D##MT, 0, 0, 0);
        FOR_MT(MF1)
        #undef MF1
        #define MF2(MT) D##MT = __builtin_amdgcn_mfma_f32_16x16x32_bf16(A##MT##_2, B2, D##MT, 0, 0, 0);
        FOR_MT(MF2)
        #undef MF2
        #define MF3(MT) D##MT = __builtin_amdgcn_mfma_f32_16x16x32_bf16(A##MT##_3, B3, D##MT, 0, 0, 0);
        FOR_MT(MF3)
        #undef MF3

        const bool cond = (t < len_n);       // per-batch freeze (uniform per lane)
        Macc += cond ? sclog : 0.0f;

        // ---- scale by EE (= exp(emit[t]) * inv_prev), pack, freeze-select ----
        #define PACKKS(KS, MTa, MTb, BV) { \
            f4v sa = D##MTa * EE##MTa; \
            f4v sb = D##MTb * EE##MTb; \
            u32 w0 = cvtpk(sa.x, sa.y), w1 = cvtpk(sa.z, sa.w); \
            u32 w2 = cvtpk(sb.x, sb.y), w3 = cvtpk(sb.z, sb.w); \
            uint4 old_ = __builtin_bit_cast(uint4, BV); \
            uint4 nw_; \
            nw_.x = cond ? w0 : old_.x;  nw_.y = cond ? w1 : old_.y; \
            nw_.z = cond ? w2 : old_.z;  nw_.w = cond ? w3 : old_.w; \
            BV = __builtin_bit_cast(s8v, nw_); }
        PACKKS(0, 0, 1, B0)
        PACKKS(1, 2, 3, B1)
        PACKKS(2, 4, 5, B2)
        PACKKS(3, 6, 7, B3)
        #undef PACKKS

        // ---- delayed normalizer for next step: inv = 1 / D[state 0][batch n] ----
        const float d00 = __shfl(D0.x, n);            // D[m=0][n] lives in lanes g=0
        const float inv_c = __builtin_amdgcn_rcpf(d00);
        sclog = -__logf(inv_c);
        // EE_next = exp(emit[t+1]) * inv_c ; shift pipeline LB <- LC
        #define EEUPD(MT) EE##MT = f4v{__expf(LB##MT.x) * inv_c, __expf(LB##MT.y) * inv_c, \
                                       __expf(LB##MT.z) * inv_c, __expf(LB##MT.w) * inv_c}; \
                          LB##MT = LC##MT;
        FOR_MT(EEUPD)
        #undef EEUPD
    }

    // ---- logZ_n = Macc_n + log( sum_k a[k] * exp(etrans[pi(k)]) ) ----
    float v = 0.0f;
    #define FDOT(KS) { uint4 bw = __builtin_bit_cast(uint4, B##KS); \
        v = dot2b(bw.x, xpack(etrans, g, KS, 0), v); \
        v = dot2b(bw.y, xpack(etrans, g, KS, 1), v); \
        v = dot2b(bw.z, xpack(etrans, g, KS, 2), v); \
        v = dot2b(bw.w, xpack(etrans, g, KS, 3), v); }
    FDOT(0) FDOT(1) FDOT(2) FDOT(3)
    #undef FDOT
    v += __shfl_xor(v, 16);
    v += __shfl_xor(v, 32);
    if (l < 16) logZ_out[bn] = Macc + __logf(v);
    #undef GATH
}

__global__ __launch_bounds__(128) void score_kernel(
        const float* __restrict__ emit,
        const int* __restrict__ target,
        const float* __restrict__ trans,
        const float* __restrict__ strans,
        const float* __restrict__ etrans,
        const int* __restrict__ lens,
        float* __restrict__ score_out) {
    const int b   = blockIdx.x;
    const int tid = threadIdx.x;  // 128
    const int len = lens[b];
    float local = 0.f;
    for (int t = tid; t < len; t += 128) {
        int tgt = target[t * B_SZ + b];
        float v = emit[(size_t)t * (B_SZ * N_ST) + b * N_ST + tgt];
        if (t > 0) v += trans[target[(t - 1) * B_SZ + b] * N_ST + tgt];
        local += v;
    }
    if (tid == 0) {
        local += strans[target[b]];
        local += etrans[target[(len - 1) * B_SZ + b]];
    }
    #pragma unroll
    for (int off = 1; off < 64; off <<= 1) local += __shfl_xor(local, off);
    __shared__ float partial[2];
    if ((tid & 63) == 0) partial[tid >> 6] = local;
    __syncthreads();
    if (tid == 0) score_out[b] = partial[0] + partial[1];
}

__global__ __launch_bounds__(256) void finalize_kernel(
        const float* __restrict__ logZ,
        const float* __restrict__ score,
        float* __restrict__ out) {
    int tid = threadIdx.x;  // 256
    float v = logZ[tid] - score[tid];
    #pragma unroll
    for (int off = 1; off < 64; off <<= 1) v += __shfl_xor(v, off);
    __shared__ float p[4];
    if ((tid & 63) == 0) p[tid >> 6] = v;
    __syncthreads();
    if (tid == 0) out[0] = (p[0] + p[1] + p[2] + p[3]) / 256.0f;
}

extern "C" void kernel_launch(void* const* d_in, const int* in_sizes, int n_in,
                              void* d_out, int out_size, void* d_ws, size_t ws_size,
                              hipStream_t stream) {
    const float*         emit   = (const float*)d_in[0];
    const int*           target = (const int*)d_in[1];
    const unsigned char* mask   = (const unsigned char*)d_in[2];
    const float*         trans  = (const float*)d_in[3];
    const float*         strans = (const float*)d_in[4];
    const float*         etrans = (const float*)d_in[5];

    float* ws     = (float*)d_ws;
    float* logZb  = ws;            // 256
    float* scoreb = ws + 256;      // 256
    int*   lens   = (int*)(ws + 512);

    lengths_kernel<<<B_SZ, 64, 0, stream>>>(mask, lens);
    forward_kernel<<<B_SZ / 16, 64, 0, stream>>>(emit, trans, strans, etrans, lens, logZb);
    score_kernel<<<B_SZ, 128, 0, stream>>>(emit, target, trans, strans, etrans, lens, scoreb);
    finalize_kernel<<<1, 256, 0, stream>>>(logZb, scoreb, (float*)d_out);
}

// Round 8
// 133.321 us; speedup vs baseline: 6.0796x; 3.3933x over previous
//
#include <hip/hip_runtime.h>

#define T_LEN 512
#define B_SZ  256
#define N_ST  128

#if defined(__has_builtin)
# if __has_builtin(__builtin_amdgcn_fdot2_f32_bf16)
#  define HAVE_DOT2 1
# endif
#endif
#ifndef HAVE_DOT2
# define HAVE_DOT2 0
#endif

typedef unsigned int uint32;
typedef __bf16 bf16x2 __attribute__((ext_vector_type(2)));

__device__ __forceinline__ uint32 bf16rn(float f) {   // RNE bf16 (no NaNs here)
    uint32 u = __builtin_bit_cast(uint32, f);
    u += 0x7fffu + ((u >> 16) & 1u);
    return u >> 16;
}
__device__ __forceinline__ uint32 pack2(float lo, float hi) {
    return bf16rn(lo) | (bf16rn(hi) << 16);
}
__device__ __forceinline__ float dot2b(uint32 a, uint32 b, float c) {
#if HAVE_DOT2
    return __builtin_amdgcn_fdot2_f32_bf16(__builtin_bit_cast(bf16x2, a),
                                           __builtin_bit_cast(bf16x2, b), c, false);
#else
    float alo = __builtin_bit_cast(float, a << 16);
    float ahi = __builtin_bit_cast(float, a & 0xffff0000u);
    float blo = __builtin_bit_cast(float, b << 16);
    float bhi = __builtin_bit_cast(float, b & 0xffff0000u);
    return fmaf(ahi, bhi, fmaf(alo, blo, c));
#endif
}

// ws layout (floats): [0..255] logZ_b ; [256..511] score_b ; [512..767] lens (int)

__global__ __launch_bounds__(64) void lengths_kernel(const unsigned char* __restrict__ mask_raw,
                                                     int* __restrict__ lens) {
    int b = blockIdx.x;   // 256 blocks
    int l = threadIdx.x;  // 64 threads
    // Detect mask encoding (mask[0][*] always true since lengths >= T/2):
    // u8: byte[1]=1 ; i32: bytes1,2=0 ; f32: 1.0f -> byte[2]=0x80
    unsigned char b1 = mask_raw[1], b2 = mask_raw[2];
    int mode = (b1 != 0) ? 0 : ((b2 != 0) ? 2 : 1);
    int cnt = 0;
    if (mode == 0) {
        #pragma unroll
        for (int k = 0; k < 8; ++k) cnt += (mask_raw[(l * 8 + k) * B_SZ + b] != 0);
    } else if (mode == 1) {
        const int* m = (const int*)mask_raw;
        #pragma unroll
        for (int k = 0; k < 8; ++k) cnt += (m[(l * 8 + k) * B_SZ + b] != 0);
    } else {
        const float* m = (const float*)mask_raw;
        #pragma unroll
        for (int k = 0; k < 8; ++k) cnt += (m[(l * 8 + k) * B_SZ + b] != 0.0f);
    }
    #pragma unroll
    for (int off = 1; off < 64; off <<= 1) cnt += __shfl_xor(cnt, off);
    if (l == 0) lens[b] = cnt;
}

// Meet-in-the-middle CRF forward: logZ = log <a_m, y_m>.
//   wave 0: a_t = ee_t o (E^T a_{t-1}),  t = 1..m        (E columns, R3 structure)
//   wave 1: y_{t-1} = E (ee_t o y_t),    t = len-1..m+1  (E rows,   mirrored)
// m = min(256, len-1): both directions <= 256 steps (len in [256,512]).
// Each wave: 128 packed-bf16 E VGPRs + dot2 inner loop + delayed uniform
// normalizer (scale by prev step's 1/r[0]; exact via Macc bookkeeping).
__global__ __launch_bounds__(128, 1) void forward_kernel(
        const float* __restrict__ emit,
        const float* __restrict__ trans,
        const float* __restrict__ strans,
        const float* __restrict__ etrans,
        const int* __restrict__ lens,
        float* __restrict__ logZ_out) {
    const int b   = blockIdx.x;
    const int tid = threadIdx.x;      // 0..127
    const int wid = tid >> 6;         // 0 = forward, 1 = backward
    const int l   = tid & 63;
    const int j0  = l, j1 = l + 64;   // owned columns (fwd) / rows (bwd)

    __shared__ alignas(16) unsigned short a16[N_ST];   // fwd vector (bf16)
    __shared__ alignas(16) unsigned short z16[N_ST];   // bwd ee*y vector (bf16)
    __shared__ float meetA[N_ST], meetY[N_ST];
    __shared__ float maccSh[2], red2[2];

    const int len = lens[b];
    const int m = (len - 1 < 256) ? (len - 1) : 256;
    const float* eb = emit + (size_t)b * N_ST;
    const size_t TS = (size_t)B_SZ * N_ST;

    if (wid == 0) {
        // ---- forward: E columns j0, j1 packed over i-pairs ----
        uint32 EA[64], EB[64];
        #pragma unroll
        for (int p = 0; p < 64; ++p) {
            EA[p] = pack2(__expf(trans[(2 * p) * N_ST + j0]), __expf(trans[(2 * p + 1) * N_ST + j0]));
            EB[p] = pack2(__expf(trans[(2 * p) * N_ST + j1]), __expf(trans[(2 * p + 1) * N_ST + j1]));
        }
        float aA = __expf(strans[j0] + eb[j0]);
        float aB = __expf(strans[j1] + eb[j1]);
        a16[j0] = (unsigned short)bf16rn(aA);
        a16[j1] = (unsigned short)bf16rn(aB);
        float Macc = 0.f, inv = 1.0f;
        float e0 = eb[TS + j0], e1 = eb[TS + j1];      // emit[1] (len >= 256)
        for (int t = 1; t <= m; ++t) {
            const int tn = (t + 1 <= m) ? t + 1 : m;
            const float en0 = eb[(size_t)tn * TS + j0], en1 = eb[(size_t)tn * TS + j1];
            const float ee0 = __expf(e0), ee1 = __expf(e1);
            float A0 = 0, A1 = 0, A2 = 0, A3 = 0, B0 = 0, B1 = 0, B2 = 0, B3 = 0;
            #pragma unroll
            for (int q = 0; q < 16; ++q) {
                uint4 w;  // alias-safe broadcast LDS read
                __builtin_memcpy(&w, (const char*)a16 + 16 * q, 16);
                A0 = dot2b(w.x, EA[4 * q + 0], A0);  B0 = dot2b(w.x, EB[4 * q + 0], B0);
                A1 = dot2b(w.y, EA[4 * q + 1], A1);  B1 = dot2b(w.y, EB[4 * q + 1], B1);
                A2 = dot2b(w.z, EA[4 * q + 2], A2);  B2 = dot2b(w.z, EB[4 * q + 2], B2);
                A3 = dot2b(w.w, EA[4 * q + 3], A3);  B3 = dot2b(w.w, EB[4 * q + 3], B3);
            }
            const float rA = (A0 + A1) + (A2 + A3);
            const float rB = (B0 + B1) + (B2 + B3);
            Macc -= __logf(inv);                       // bookkeeping for applied scale
            aA = ee0 * rA * inv;                       // delayed uniform normalizer
            aB = ee1 * rB * inv;
            a16[j0] = (unsigned short)bf16rn(aA);      // wave-internal DS order: no barrier
            a16[j1] = (unsigned short)bf16rn(aB);
            inv = __builtin_amdgcn_rcpf(__shfl(rA, 0));  // for NEXT step (off write path)
            e0 = en0; e1 = en1;
        }
        meetA[j0] = aA; meetA[j1] = aB;
        if (l == 0) maccSh[0] = Macc;
    } else {
        // ---- backward: E rows j0, j1 packed over j-pairs ----
        uint32 RA[64], RB[64];
        #pragma unroll
        for (int p = 0; p < 64; ++p) {
            RA[p] = pack2(__expf(trans[j0 * N_ST + 2 * p]), __expf(trans[j0 * N_ST + 2 * p + 1]));
            RB[p] = pack2(__expf(trans[j1 * N_ST + 2 * p]), __expf(trans[j1 * N_ST + 2 * p + 1]));
        }
        float y0 = __expf(etrans[j0]);                 // y_{len-1} = exp(etrans)
        float y1 = __expf(etrans[j1]);
        float Maccb = 0.f, invb = 1.0f;
        const int t0 = len - 1;
        float e0 = eb[(size_t)t0 * TS + j0], e1 = eb[(size_t)t0 * TS + j1];
        for (int t = t0; t > m; --t) {
            const int tn = (t - 1 > m) ? t - 1 : m + 1;
            const float en0 = eb[(size_t)tn * TS + j0], en1 = eb[(size_t)tn * TS + j1];
            const float ee0 = __expf(e0), ee1 = __expf(e1);
            z16[j0] = (unsigned short)bf16rn(ee0 * y0);   // z = ee_t o y_t
            z16[j1] = (unsigned short)bf16rn(ee1 * y1);
            float R0 = 0, R1 = 0, R2 = 0, R3 = 0, S0 = 0, S1 = 0, S2 = 0, S3 = 0;
            #pragma unroll
            for (int q = 0; q < 16; ++q) {
                uint4 w;
                __builtin_memcpy(&w, (const char*)z16 + 16 * q, 16);
                R0 = dot2b(w.x, RA[4 * q + 0], R0);  S0 = dot2b(w.x, RB[4 * q + 0], S0);
                R1 = dot2b(w.y, RA[4 * q + 1], R1);  S1 = dot2b(w.y, RB[4 * q + 1], S1);
                R2 = dot2b(w.z, RA[4 * q + 2], R2);  S2 = dot2b(w.z, RB[4 * q + 2], S2);
                R3 = dot2b(w.w, RA[4 * q + 3], R3);  S3 = dot2b(w.w, RB[4 * q + 3], S3);
            }
            const float rR = (R0 + R1) + (R2 + R3);
            const float rS = (S0 + S1) + (S2 + S3);
            Maccb -= __logf(invb);
            y0 = rR * invb;                            // delayed normalizer, mirrored
            y1 = rS * invb;
            invb = __builtin_amdgcn_rcpf(__shfl(rR, 0));
            e0 = en0; e1 = en1;
        }
        meetY[j0] = y0; meetY[j1] = y1;
        if (l == 0) maccSh[1] = Maccb;
    }

    // ---- meet: logZ = MaccF + MaccB + log( sum_j a_m[j] * y_m[j] ) ----
    __syncthreads();
    float v = meetA[tid] * meetY[tid];
    #pragma unroll
    for (int off = 1; off < 64; off <<= 1) v += __shfl_xor(v, off);
    if (l == 0) red2[wid] = v;
    __syncthreads();
    if (tid == 0) logZ_out[b] = maccSh[0] + maccSh[1] + __logf(red2[0] + red2[1]);
}

__global__ __launch_bounds__(128) void score_kernel(
        const float* __restrict__ emit,
        const int* __restrict__ target,
        const float* __restrict__ trans,
        const float* __restrict__ strans,
        const float* __restrict__ etrans,
        const int* __restrict__ lens,
        float* __restrict__ score_out) {
    const int b   = blockIdx.x;
    const int tid = threadIdx.x;  // 128
    const int len = lens[b];
    float local = 0.f;
    for (int t = tid; t < len; t += 128) {
        int tgt = target[t * B_SZ + b];
        float v = emit[(size_t)t * (B_SZ * N_ST) + b * N_ST + tgt];
        if (t > 0) v += trans[target[(t - 1) * B_SZ + b] * N_ST + tgt];
        local += v;
    }
    if (tid == 0) {
        local += strans[target[b]];
        local += etrans[target[(len - 1) * B_SZ + b]];
    }
    #pragma unroll
    for (int off = 1; off < 64; off <<= 1) local += __shfl_xor(local, off);
    __shared__ float partial[2];
    if ((tid & 63) == 0) partial[tid >> 6] = local;
    __syncthreads();
    if (tid == 0) score_out[b] = partial[0] + partial[1];
}

__global__ __launch_bounds__(256) void finalize_kernel(
        const float* __restrict__ logZ,
        const float* __restrict__ score,
        float* __restrict__ out) {
    int tid = threadIdx.x;  // 256
    float v = logZ[tid] - score[tid];
    #pragma unroll
    for (int off = 1; off < 64; off <<= 1) v += __shfl_xor(v, off);
    __shared__ float p[4];
    if ((tid & 63) == 0) p[tid >> 6] = v;
    __syncthreads();
    if (tid == 0) out[0] = (p[0] + p[1] + p[2] + p[3]) / 256.0f;
}

extern "C" void kernel_launch(void* const* d_in, const int* in_sizes, int n_in,
                              void* d_out, int out_size, void* d_ws, size_t ws_size,
                              hipStream_t stream) {
    const float*         emit   = (const float*)d_in[0];
    const int*           target = (const int*)d_in[1];
    const unsigned char* mask   = (const unsigned char*)d_in[2];
    const float*         trans  = (const float*)d_in[3];
    const float*         strans = (const float*)d_in[4];
    const float*         etrans = (const float*)d_in[5];

    float* ws     = (float*)d_ws;
    float* logZb  = ws;            // 256
    float* scoreb = ws + 256;      // 256
    int*   lens   = (int*)(ws + 512);

    lengths_kernel<<<B_SZ, 64, 0, stream>>>(mask, lens);
    forward_kernel<<<B_SZ, 128, 0, stream>>>(emit, trans, strans, etrans, lens, logZb);
    score_kernel<<<B_SZ, 128, 0, stream>>>(emit, target, trans, strans, etrans, lens, scoreb);
    finalize_kernel<<<1, 256, 0, stream>>>(logZb, scoreb, (float*)d_out);
}

// Round 9
// 125.883 us; speedup vs baseline: 6.4388x; 1.0591x over previous
//
#include <hip/hip_runtime.h>

#define T_LEN 512
#define B_SZ  256
#define N_ST  128

#if defined(__has_builtin)
# if __has_builtin(__builtin_amdgcn_fdot2_f32_bf16)
#  define HAVE_DOT2 1
# endif
#endif
#ifndef HAVE_DOT2
# define HAVE_DOT2 0
#endif

typedef unsigned int uint32;
typedef __bf16 bf16x2 __attribute__((ext_vector_type(2)));

__device__ __forceinline__ uint32 bf16rn(float f) {   // RNE bf16 (no NaNs here)
    uint32 u = __builtin_bit_cast(uint32, f);
    u += 0x7fffu + ((u >> 16) & 1u);
    return u >> 16;
}
__device__ __forceinline__ uint32 pack2(float lo, float hi) {
    return bf16rn(lo) | (bf16rn(hi) << 16);
}
__device__ __forceinline__ uint32 cvtpk(float lo, float hi) {   // HW packed cvt, RNE
    uint32 r;
    asm("v_cvt_pk_bf16_f32 %0, %1, %2" : "=v"(r) : "v"(lo), "v"(hi));
    return r;
}
__device__ __forceinline__ float readlane0(float v) {   // lane 0 -> SGPR (NOT the DS pipe)
    return __builtin_bit_cast(float, (uint32)__builtin_amdgcn_readlane(__builtin_bit_cast(int, v), 0));
}
__device__ __forceinline__ float dot2b(uint32 a, uint32 b, float c) {
#if HAVE_DOT2
    return __builtin_amdgcn_fdot2_f32_bf16(__builtin_bit_cast(bf16x2, a),
                                           __builtin_bit_cast(bf16x2, b), c, false);
#else
    float alo = __builtin_bit_cast(float, a << 16);
    float ahi = __builtin_bit_cast(float, a & 0xffff0000u);
    float blo = __builtin_bit_cast(float, b << 16);
    float bhi = __builtin_bit_cast(float, b & 0xffff0000u);
    return fmaf(ahi, bhi, fmaf(alo, blo, c));
#endif
}

// ws layout (floats): [0..255] logZ_b ; [256..511] score_b ; [512..767] lens (int)

__global__ __launch_bounds__(64) void lengths_kernel(const unsigned char* __restrict__ mask_raw,
                                                     int* __restrict__ lens) {
    int b = blockIdx.x;   // 256 blocks
    int l = threadIdx.x;  // 64 threads
    // Detect mask encoding (mask[0][*] always true since lengths >= T/2):
    // u8: byte[1]=1 ; i32: bytes1,2=0 ; f32: 1.0f -> byte[2]=0x80
    unsigned char b1 = mask_raw[1], b2 = mask_raw[2];
    int mode = (b1 != 0) ? 0 : ((b2 != 0) ? 2 : 1);
    int cnt = 0;
    if (mode == 0) {
        #pragma unroll
        for (int k = 0; k < 8; ++k) cnt += (mask_raw[(l * 8 + k) * B_SZ + b] != 0);
    } else if (mode == 1) {
        const int* m = (const int*)mask_raw;
        #pragma unroll
        for (int k = 0; k < 8; ++k) cnt += (m[(l * 8 + k) * B_SZ + b] != 0);
    } else {
        const float* m = (const float*)mask_raw;
        #pragma unroll
        for (int k = 0; k < 8; ++k) cnt += (m[(l * 8 + k) * B_SZ + b] != 0.0f);
    }
    #pragma unroll
    for (int off = 1; off < 64; off <<= 1) cnt += __shfl_xor(cnt, off);
    if (l == 0) lens[b] = cnt;
}

// Meet-in-the-middle CRF forward: logZ = log <a_m, y_m>.
//   wave 0: a_t = ee_t o (E^T a_{t-1}),  t = 1..m        (E columns)
//   wave 1: y_{t-1} = E (ee_t o y_t),    t = len-1..m+1  (E rows)
// m = min(256, len-1). Per-step latency diet vs R8:
//  - normalizer via v_readlane (scalar) instead of __shfl/ds_bpermute (DS pipe)
//  - lane owns ADJACENT cols (2l, 2l+1): state update = ONE ds_write_b32 (cvt_pk)
//  - 2-deep emit prefetch so no per-step vmcnt stall even with lazy drains
__global__ __launch_bounds__(128, 1) void forward_kernel(
        const float* __restrict__ emit,
        const float* __restrict__ trans,
        const float* __restrict__ strans,
        const float* __restrict__ etrans,
        const int* __restrict__ lens,
        float* __restrict__ logZ_out) {
    const int b   = blockIdx.x;
    const int tid = threadIdx.x;      // 0..127
    const int wid = tid >> 6;         // 0 = forward, 1 = backward
    const int l   = tid & 63;
    const int c0  = 2 * l, c1 = 2 * l + 1;   // owned cols (fwd) / rows (bwd)

    __shared__ alignas(16) uint32 a32[64];   // fwd a-vector, bf16x2 packed
    __shared__ alignas(16) uint32 z32[64];   // bwd ee*y vector, bf16x2 packed
    __shared__ float meetA[N_ST], meetY[N_ST];
    __shared__ float maccSh[2], red2[2];

    const int len = lens[b];
    const int m = (len - 1 < 256) ? (len - 1) : 256;
    const float* eb = emit + (size_t)b * N_ST;
    const size_t TS = (size_t)B_SZ * N_ST;

    if (wid == 0) {
        // ---- forward: E columns c0, c1 packed over i-pairs ----
        uint32 EA[64], EB[64];
        #pragma unroll
        for (int p = 0; p < 64; ++p) {
            EA[p] = pack2(__expf(trans[(2 * p) * N_ST + c0]), __expf(trans[(2 * p + 1) * N_ST + c0]));
            EB[p] = pack2(__expf(trans[(2 * p) * N_ST + c1]), __expf(trans[(2 * p + 1) * N_ST + c1]));
        }
        float aA = __expf(strans[c0] + eb[c0]);
        float aB = __expf(strans[c1] + eb[c1]);
        a32[l] = pack2(aA, aB);
        float Macc = 0.f, inv = 1.0f;
        // 2-deep emit pipeline: e_cur = emit[t], e_nx = emit[t+1]
        float ec0 = eb[TS + c0],      ec1 = eb[TS + c1];        // emit[1]
        float en0 = eb[2 * TS + c0],  en1 = eb[2 * TS + c1];    // emit[2] (len>=256)
        for (int t = 1; t <= m; ++t) {
            const size_t t2 = (size_t)((t + 2 <= m) ? t + 2 : m) * TS;
            const float e20 = eb[t2 + c0], e21 = eb[t2 + c1];   // prefetch, 2 iters ahead
            const float ee0 = __expf(ec0), ee1 = __expf(ec1);
            float A0 = 0, A1 = 0, A2 = 0, A3 = 0, B0 = 0, B1 = 0, B2 = 0, B3 = 0;
            #pragma unroll
            for (int q = 0; q < 16; ++q) {
                uint4 w;  // alias-safe broadcast LDS read
                __builtin_memcpy(&w, (const char*)a32 + 16 * q, 16);
                A0 = dot2b(w.x, EA[4 * q + 0], A0);  B0 = dot2b(w.x, EB[4 * q + 0], B0);
                A1 = dot2b(w.y, EA[4 * q + 1], A1);  B1 = dot2b(w.y, EB[4 * q + 1], B1);
                A2 = dot2b(w.z, EA[4 * q + 2], A2);  B2 = dot2b(w.z, EB[4 * q + 2], B2);
                A3 = dot2b(w.w, EA[4 * q + 3], A3);  B3 = dot2b(w.w, EB[4 * q + 3], B3);
            }
            const float rA = (A0 + A1) + (A2 + A3);
            const float rB = (B0 + B1) + (B2 + B3);
            Macc -= __logf(inv);                       // bookkeeping (off write path)
            aA = ee0 * rA * inv;                       // delayed uniform normalizer
            aB = ee1 * rB * inv;
            a32[l] = cvtpk(aA, aB);                    // ONE ds_write_b32
            inv = __builtin_amdgcn_rcpf(readlane0(rA));  // scalar path, NOT DS pipe
            ec0 = en0; ec1 = en1; en0 = e20; en1 = e21;
        }
        meetA[c0] = aA; meetA[c1] = aB;
        if (l == 0) maccSh[0] = Macc;
    } else {
        // ---- backward: E rows c0, c1 packed over j-pairs (contiguous trans reads) ----
        uint32 RA[64], RB[64];
        #pragma unroll
        for (int p = 0; p < 64; ++p) {
            RA[p] = pack2(__expf(trans[c0 * N_ST + 2 * p]), __expf(trans[c0 * N_ST + 2 * p + 1]));
            RB[p] = pack2(__expf(trans[c1 * N_ST + 2 * p]), __expf(trans[c1 * N_ST + 2 * p + 1]));
        }
        float y0 = __expf(etrans[c0]);                 // y_{len-1} = exp(etrans)
        float y1 = __expf(etrans[c1]);
        float Maccb = 0.f, invb = 1.0f;
        const int t0 = len - 1;
        float ec0 = eb[(size_t)t0 * TS + c0], ec1 = eb[(size_t)t0 * TS + c1];
        float en0 = ec0, en1 = ec1;
        if (t0 - 1 > m) { en0 = eb[(size_t)(t0 - 1) * TS + c0]; en1 = eb[(size_t)(t0 - 1) * TS + c1]; }
        for (int t = t0; t > m; --t) {
            const int tp = (t - 2 > m) ? t - 2 : m + 1;
            const float e20 = eb[(size_t)tp * TS + c0], e21 = eb[(size_t)tp * TS + c1];
            const float ee0 = __expf(ec0), ee1 = __expf(ec1);
            z32[l] = cvtpk(ee0 * y0, ee1 * y1);        // z = ee_t o y_t ; ONE write
            float R0 = 0, R1 = 0, R2 = 0, R3 = 0, S0 = 0, S1 = 0, S2 = 0, S3 = 0;
            #pragma unroll
            for (int q = 0; q < 16; ++q) {
                uint4 w;
                __builtin_memcpy(&w, (const char*)z32 + 16 * q, 16);
                R0 = dot2b(w.x, RA[4 * q + 0], R0);  S0 = dot2b(w.x, RB[4 * q + 0], S0);
                R1 = dot2b(w.y, RA[4 * q + 1], R1);  S1 = dot2b(w.y, RB[4 * q + 1], S1);
                R2 = dot2b(w.z, RA[4 * q + 2], R2);  S2 = dot2b(w.z, RB[4 * q + 2], S2);
                R3 = dot2b(w.w, RA[4 * q + 3], R3);  S3 = dot2b(w.w, RB[4 * q + 3], S3);
            }
            const float rR = (R0 + R1) + (R2 + R3);
            const float rS = (S0 + S1) + (S2 + S3);
            Maccb -= __logf(invb);
            y0 = rR * invb;                            // delayed normalizer, mirrored
            y1 = rS * invb;
            invb = __builtin_amdgcn_rcpf(readlane0(rR));
            ec0 = en0; ec1 = en1; en0 = e20; en1 = e21;
        }
        meetY[c0] = y0; meetY[c1] = y1;
        if (l == 0) maccSh[1] = Maccb;
    }

    // ---- meet: logZ = MaccF + MaccB + log( sum_j a_m[j] * y_m[j] ) ----
    __syncthreads();
    float v = meetA[tid] * meetY[tid];
    #pragma unroll
    for (int off = 1; off < 64; off <<= 1) v += __shfl_xor(v, off);
    if (l == 0) red2[wid] = v;
    __syncthreads();
    if (tid == 0) logZ_out[b] = maccSh[0] + maccSh[1] + __logf(red2[0] + red2[1]);
}

__global__ __launch_bounds__(128) void score_kernel(
        const float* __restrict__ emit,
        const int* __restrict__ target,
        const float* __restrict__ trans,
        const float* __restrict__ strans,
        const float* __restrict__ etrans,
        const int* __restrict__ lens,
        float* __restrict__ score_out) {
    const int b   = blockIdx.x;
    const int tid = threadIdx.x;  // 128
    const int len = lens[b];
    float local = 0.f;
    for (int t = tid; t < len; t += 128) {
        int tgt = target[t * B_SZ + b];
        float v = emit[(size_t)t * (B_SZ * N_ST) + b * N_ST + tgt];
        if (t > 0) v += trans[target[(t - 1) * B_SZ + b] * N_ST + tgt];
        local += v;
    }
    if (tid == 0) {
        local += strans[target[b]];
        local += etrans[target[(len - 1) * B_SZ + b]];
    }
    #pragma unroll
    for (int off = 1; off < 64; off <<= 1) local += __shfl_xor(local, off);
    __shared__ float partial[2];
    if ((tid & 63) == 0) partial[tid >> 6] = local;
    __syncthreads();
    if (tid == 0) score_out[b] = partial[0] + partial[1];
}

__global__ __launch_bounds__(256) void finalize_kernel(
        const float* __restrict__ logZ,
        const float* __restrict__ score,
        float* __restrict__ out) {
    int tid = threadIdx.x;  // 256
    float v = logZ[tid] - score[tid];
    #pragma unroll
    for (int off = 1; off < 64; off <<= 1) v += __shfl_xor(v, off);
    __shared__ float p[4];
    if ((tid & 63) == 0) p[tid >> 6] = v;
    __syncthreads();
    if (tid == 0) out[0] = (p[0] + p[1] + p[2] + p[3]) / 256.0f;
}

extern "C" void kernel_launch(void* const* d_in, const int* in_sizes, int n_in,
                              void* d_out, int out_size, void* d_ws, size_t ws_size,
                              hipStream_t stream) {
    const float*         emit   = (const float*)d_in[0];
    const int*           target = (const int*)d_in[1];
    const unsigned char* mask   = (const unsigned char*)d_in[2];
    const float*         trans  = (const float*)d_in[3];
    const float*         strans = (const float*)d_in[4];
    const float*         etrans = (const float*)d_in[5];

    float* ws     = (float*)d_ws;
    float* logZb  = ws;            // 256
    float* scoreb = ws + 256;      // 256
    int*   lens   = (int*)(ws + 512);

    lengths_kernel<<<B_SZ, 64, 0, stream>>>(mask, lens);
    forward_kernel<<<B_SZ, 128, 0, stream>>>(emit, trans, strans, etrans, lens, logZb);
    score_kernel<<<B_SZ, 128, 0, stream>>>(emit, target, trans, strans, etrans, lens, scoreb);
    finalize_kernel<<<1, 256, 0, stream>>>(logZb, scoreb, (float*)d_out);
}